// Round 8
// baseline (461.651 us; speedup 1.0000x reference)
//
#include <hip/hip_runtime.h>

#define NLVL 16
#define T_MASK ((1u << 19) - 1)
#define NBIN 32768   // 32^3 Morton bins

typedef float v2f __attribute__((ext_vector_type(2)));
typedef float v4f __attribute__((ext_vector_type(4)));

// Runtime-indexed copies (hash kernel, fallback)
__constant__ int c_res[NLVL] = {16, 20, 25, 32, 40, 50, 64, 80,
                                101, 128, 161, 203, 256, 322, 406, 512};
__constant__ int c_off[NLVL] = {0, 4913, 14174, 31750, 67687, 136608, 269259, 543884,
                                1075325, 1599613, 2123901, 2648189, 3172477, 3696765, 4221053, 4745341};
__constant__ float c_grid[NLVL] = {
    (float)(2.0 / 16.0),  (float)(2.0 / 20.0),  (float)(2.0 / 25.0),  (float)(2.0 / 32.0),
    (float)(2.0 / 40.0),  (float)(2.0 / 50.0),  (float)(2.0 / 64.0),  (float)(2.0 / 80.0),
    (float)(2.0 / 101.0), (float)(2.0 / 128.0), (float)(2.0 / 161.0), (float)(2.0 / 203.0),
    (float)(2.0 / 256.0), (float)(2.0 / 322.0), (float)(2.0 / 406.0), (float)(2.0 / 512.0)};

// Compile-time copies (dense kernel, fully unrolled -> immediates)
constexpr int kRes[8] = {16, 20, 25, 32, 40, 50, 64, 80};
constexpr int kOff[8] = {0, 4913, 14174, 31750, 67687, 136608, 269259, 543884};
constexpr float kGrid[8] = {
    (float)(2.0 / 16.0), (float)(2.0 / 20.0), (float)(2.0 / 25.0), (float)(2.0 / 32.0),
    (float)(2.0 / 40.0), (float)(2.0 / 50.0), (float)(2.0 / 64.0), (float)(2.0 / 80.0)};

__device__ __forceinline__ void dim_setup(float xv, float grid, int& b, float& w) {
    float xc = fminf(fmaxf(xv, -1.0f), 1.0f);
    float fb = floorf((xc + 1.0f) / grid);
    b = (int)fb;
    float vmin = fb * grid - 1.0f;
    w = (xv - vmin) / grid;   // original xv, exactly as reference
}

__device__ __forceinline__ unsigned part1by2(unsigned v) {
    v &= 0x3ff;
    v = (v | (v << 16)) & 0x030000FFu;
    v = (v | (v << 8))  & 0x0300F00Fu;
    v = (v | (v << 4))  & 0x030C30C3u;
    v = (v | (v << 2))  & 0x09249249u;
    return v;
}

__device__ __forceinline__ unsigned bin3(float a, float b, float c) {
    int ba = (int)floorf((a + 1.0f) * 16.0f); ba = ba < 0 ? 0 : (ba > 31 ? 31 : ba);
    int bb = (int)floorf((b + 1.0f) * 16.0f); bb = bb < 0 ? 0 : (bb > 31 ? 31 : bb);
    int bc = (int)floorf((c + 1.0f) * 16.0f); bc = bc < 0 ? 0 : (bc > 31 ? 31 : bc);
    return part1by2((unsigned)ba) | (part1by2((unsigned)bb) << 1) | (part1by2((unsigned)bc) << 2);
}

// ---- hashed levels + fused histogram (UNSORTED: hash gathers are random
// regardless of point order; table L2-residency comes from XCD affinity,
// not sorting). level = (blockIdx&7)+8 -> one 4 MB table per XCD. Each
// chunk's histogram duty is done by exactly one of its 8 level-blocks,
// rotated by (chunk&7) so atomics spread evenly across XCDs.
__global__ __launch_bounds__(256) void gather_hash_u(const float* __restrict__ x,
                                                     const float* __restrict__ tables,
                                                     v2f* __restrict__ ws2,
                                                     unsigned* __restrict__ hist, int n) {
    __shared__ float sx[768];
    const int level = (int)(blockIdx.x & 7) + 8;
    const int chunk = (int)(blockIdx.x >> 3);
    const int p0 = chunk * 256;
    const int tid = (int)threadIdx.x;

    for (int i = tid; i < 768; i += 256) {
        int gi = p0 * 3 + i;
        sx[i] = (gi < n * 3) ? x[gi] : 0.0f;
    }
    __syncthreads();

    const int p = p0 + tid;
    if (p >= n) return;

    const float xx = sx[tid * 3 + 0];
    const float xy = sx[tid * 3 + 1];
    const float xz = sx[tid * 3 + 2];

    if ((int)(blockIdx.x & 7) == (chunk & 7))
        atomicAdd(&hist[bin3(xx, xy, xz)], 1u);

    const float grid = c_grid[level];
    const v2f* __restrict__ tab = reinterpret_cast<const v2f*>(tables) + c_off[level];

    int bx, by, bz;
    float wx, wy, wz;
    dim_setup(xx, grid, bx, wx);
    dim_setup(xy, grid, by, wy);
    dim_setup(xz, grid, bz, wz);

    const unsigned hx0 = (unsigned)bx, hx1 = (unsigned)(bx + 1);
    const unsigned hy0 = (unsigned)by * 2654435761u;
    const unsigned hy1 = (unsigned)(by + 1) * 2654435761u;
    const unsigned hz0 = (unsigned)bz * 805459861u;
    const unsigned hz1 = (unsigned)(bz + 1) * 805459861u;
    v2f e0 = tab[(hx0 ^ hy0 ^ hz0) & T_MASK];
    v2f e1 = tab[(hx0 ^ hy0 ^ hz1) & T_MASK];
    v2f e2 = tab[(hx0 ^ hy1 ^ hz0) & T_MASK];
    v2f e3 = tab[(hx0 ^ hy1 ^ hz1) & T_MASK];
    v2f e4 = tab[(hx1 ^ hy0 ^ hz0) & T_MASK];
    v2f e5 = tab[(hx1 ^ hy0 ^ hz1) & T_MASK];
    v2f e6 = tab[(hx1 ^ hy1 ^ hz0) & T_MASK];
    v2f e7 = tab[(hx1 ^ hy1 ^ hz1) & T_MASK];

    const float ox = 1.0f - wx, oy = 1.0f - wy, oz = 1.0f - wz;
    v2f c00 = e0 * ox + e4 * wx;
    v2f c01 = e1 * ox + e5 * wx;
    v2f c10 = e2 * ox + e6 * wx;
    v2f c11 = e3 * ox + e7 * wx;
    v2f c0 = c00 * oy + c10 * wy;
    v2f c1 = c01 * oy + c11 * wy;
    v2f r = c0 * oz + c1 * wz;

    // original point order; lane-contiguous -> full-line coalescing
    __builtin_nontemporal_store(r, &ws2[(size_t)(level - 8) * n + p]);
}

// ---- LDS-resident scan over 32K bins (one block, 1024 threads). ----------
// Global reads/writes fully coalesced; chunk scan uses +1-per-32 padding so
// the 32-lane strided reads are conflict-free.
__global__ __launch_bounds__(1024) void scan_kernel(const unsigned* __restrict__ hist,
                                                    unsigned* __restrict__ base) {
    __shared__ unsigned lh[NBIN + NBIN / 32];   // addr = g + (g>>5)
    __shared__ unsigned part[1024];
    __shared__ unsigned cbase[1024];
    const int t = (int)threadIdx.x;

#pragma unroll
    for (int i = 0; i < NBIN / 1024; ++i) {
        int g = i * 1024 + t;
        lh[g + (g >> 5)] = hist[g];
    }
    __syncthreads();

    // exclusive scan of this thread's 32 contiguous bins (padded base t*33)
    unsigned run = 0;
#pragma unroll
    for (int i = 0; i < 32; ++i) {
        unsigned v = lh[t * 33 + i];
        lh[t * 33 + i] = run;
        run += v;
    }
    part[t] = run;
    __syncthreads();

    // inclusive ladder scan of the 1024 chunk totals
    for (int off = 1; off < 1024; off <<= 1) {
        unsigned v = (t >= off) ? part[t - off] : 0u;
        __syncthreads();
        part[t] += v;
        __syncthreads();
    }
    cbase[t] = part[t] - run;   // exclusive base of chunk t
    __syncthreads();

#pragma unroll
    for (int i = 0; i < NBIN / 1024; ++i) {
        int g = i * 1024 + t;
        base[g] = lh[g + (g >> 5)] + cbase[g >> 5];
    }
}

__global__ __launch_bounds__(256) void scatter_kernel(const float* __restrict__ x,
                                                      unsigned* __restrict__ base,
                                                      v4f* __restrict__ pts, int n) {
    int p = (int)blockIdx.x * 256 + (int)threadIdx.x;
    if (p >= n) return;
    float a = x[3 * p], b = x[3 * p + 1], c = x[3 * p + 2];
    unsigned slot = atomicAdd(&base[bin3(a, b, c)], 1u);
    v4f v; v.x = a; v.y = b; v.z = c; v.w = __int_as_float(p);
    pts[slot] = v;
}

// ---- dense levels, sorted points; writes FIRST 64 B of each output row ---
// LDS-staged so every 64 B line is covered by one store instruction.
#define RS2 20   // floats per LDS row slot (80 B)
__global__ __launch_bounds__(256, 4) void dense_store(const v4f* __restrict__ pts,
                                                      const float* __restrict__ tables,
                                                      float* __restrict__ out, int n) {
    __shared__ float lrow[256 * RS2];   // 20 KB
    __shared__ int lorg[256];

    const int nb = (int)gridDim.x;
    const int bid = (int)blockIdx.x;
    const int q = nb >> 3, r = nb & 7;
    const int xcd = bid & 7, j = bid >> 3;
    const int nbid = (xcd < r) ? xcd * (q + 1) + j : r * (q + 1) + (xcd - r) * q + j;
    const int tid = (int)threadIdx.x;
    const int base_p = nbid * 256;
    const int p = base_p + tid;

    if (p < n) {
        const v4f pt = __builtin_nontemporal_load(&pts[p]);
        lorg[tid] = __float_as_int(pt.w);

        v2f d[8];
#pragma unroll
        for (int l = 0; l < 8; ++l) {
            const int res = kRes[l];
            const float grid = kGrid[l];
            const v2f* __restrict__ tab = reinterpret_cast<const v2f*>(tables) + kOff[l];
            int bx, by, bz;
            float wx, wy, wz;
            dim_setup(pt.x, grid, bx, wx);
            dim_setup(pt.y, grid, by, wy);
            dim_setup(pt.z, grid, bz, wz);
            const int r2 = res * res;
            const int base = bx * r2 + by * res + bz;
            v2f e0 = tab[base];            v2f e1 = tab[base + 1];
            v2f e2 = tab[base + res];      v2f e3 = tab[base + res + 1];
            v2f e4 = tab[base + r2];       v2f e5 = tab[base + r2 + 1];
            v2f e6 = tab[base + r2 + res]; v2f e7 = tab[base + r2 + res + 1];
            const float ox = 1.0f - wx, oy = 1.0f - wy, oz = 1.0f - wz;
            v2f c00 = e0 * ox + e4 * wx;
            v2f c01 = e1 * ox + e5 * wx;
            v2f c10 = e2 * ox + e6 * wx;
            v2f c11 = e3 * ox + e7 * wx;
            v2f c0 = c00 * oy + c10 * wy;
            v2f c1 = c01 * oy + c11 * wy;
            d[l] = c0 * oz + c1 * wz;
        }

        float* myrow = &lrow[tid * RS2];
#pragma unroll
        for (int k = 0; k < 4; ++k) {
            v4f v; v.x = d[2 * k].x; v.y = d[2 * k].y; v.z = d[2 * k + 1].x; v.w = d[2 * k + 1].y;
            *reinterpret_cast<v4f*>(myrow + 4 * k) = v;
        }
    }
    __syncthreads();

    // 4 lanes per row: each 64 B line covered by one instruction
    const int c = tid & 3;
    const int r0 = tid >> 2;
#pragma unroll
    for (int s = 0; s < 4; ++s) {
        const int rr = s * 64 + r0;
        if (base_p + rr < n) {
            v4f v = *reinterpret_cast<const v4f*>(&lrow[rr * RS2 + c * 4]);
            const int o = lorg[rr];
            *reinterpret_cast<v4f*>(out + (size_t)o * 32 + c * 4) = v;
        }
    }
}

// ---- hashed half: ws2 (original order) -> SECOND 64 B of each row --------
// Both sides coalesced; no org indirection needed.
__global__ __launch_bounds__(256) void hash_store(const v2f* __restrict__ ws2,
                                                  float* __restrict__ out, int n) {
    __shared__ float lrow[256 * RS2];   // 20 KB
    const int p0 = (int)blockIdx.x * 256;
    const int tid = (int)threadIdx.x;
    const int p = p0 + tid;

    if (p < n) {
        float* myrow = &lrow[tid * RS2];
#pragma unroll
        for (int l = 0; l < 4; ++l) {
            v2f a = __builtin_nontemporal_load(&ws2[(size_t)(2 * l) * n + p]);
            v2f b = __builtin_nontemporal_load(&ws2[(size_t)(2 * l + 1) * n + p]);
            v4f v; v.x = a.x; v.y = a.y; v.z = b.x; v.w = b.y;
            *reinterpret_cast<v4f*>(myrow + 4 * l) = v;
        }
    }
    __syncthreads();

    const int c = tid & 3;
    const int r0 = tid >> 2;
#pragma unroll
    for (int s = 0; s < 4; ++s) {
        const int rr = s * 64 + r0;
        if (p0 + rr < n) {
            v4f v = *reinterpret_cast<const v4f*>(&lrow[rr * RS2 + c * 4]);
            *reinterpret_cast<v4f*>(out + (size_t)(p0 + rr) * 32 + 16 + c * 4) = v;
        }
    }
}

// ---- safety fallback (ws too small) --------------------------------------
__global__ __launch_bounds__(256) void hashgrid_direct(const float* __restrict__ x,
                                                       const float* __restrict__ tables,
                                                       float* __restrict__ out, int n_points) {
    const int t = (int)blockIdx.x * 256 + (int)threadIdx.x;
    const int p = t >> 4;
    if (p >= n_points) return;
    const int l = t & 15;
    const float xx = x[p * 3 + 0], xy = x[p * 3 + 1], xz = x[p * 3 + 2];
    const int res = c_res[l];
    const float grid = c_grid[l];
    const v2f* __restrict__ tab = reinterpret_cast<const v2f*>(tables) + c_off[l];
    int bx, by, bz; float wx, wy, wz;
    dim_setup(xx, grid, bx, wx);
    dim_setup(xy, grid, by, wy);
    dim_setup(xz, grid, bz, wz);
    v2f e0, e1, e2, e3, e4, e5, e6, e7;
    if (l < 8) {
        const int r2 = res * res;
        const int base = bx * r2 + by * res + bz;
        e0 = tab[base];            e1 = tab[base + 1];
        e2 = tab[base + res];      e3 = tab[base + res + 1];
        e4 = tab[base + r2];       e5 = tab[base + r2 + 1];
        e6 = tab[base + r2 + res]; e7 = tab[base + r2 + res + 1];
    } else {
        const unsigned hx0 = (unsigned)bx, hx1 = (unsigned)(bx + 1);
        const unsigned hy0 = (unsigned)by * 2654435761u, hy1 = (unsigned)(by + 1) * 2654435761u;
        const unsigned hz0 = (unsigned)bz * 805459861u,  hz1 = (unsigned)(bz + 1) * 805459861u;
        e0 = tab[(hx0 ^ hy0 ^ hz0) & T_MASK]; e1 = tab[(hx0 ^ hy0 ^ hz1) & T_MASK];
        e2 = tab[(hx0 ^ hy1 ^ hz0) & T_MASK]; e3 = tab[(hx0 ^ hy1 ^ hz1) & T_MASK];
        e4 = tab[(hx1 ^ hy0 ^ hz0) & T_MASK]; e5 = tab[(hx1 ^ hy0 ^ hz1) & T_MASK];
        e6 = tab[(hx1 ^ hy1 ^ hz0) & T_MASK]; e7 = tab[(hx1 ^ hy1 ^ hz1) & T_MASK];
    }
    const float ox = 1.0f - wx, oy = 1.0f - wy, oz = 1.0f - wz;
    v2f c00 = e0 * ox + e4 * wx, c01 = e1 * ox + e5 * wx;
    v2f c10 = e2 * ox + e6 * wx, c11 = e3 * ox + e7 * wx;
    v2f c0 = c00 * oy + c10 * wy, c1 = c01 * oy + c11 * wy;
    v2f r = c0 * oz + c1 * wz;
    reinterpret_cast<v2f*>(out)[(size_t)p * NLVL + l] = r;
}

extern "C" void kernel_launch(void* const* d_in, const int* in_sizes, int n_in,
                              void* d_out, int out_size, void* d_ws, size_t ws_size,
                              hipStream_t stream) {
    const float* x = (const float*)d_in[0];
    const float* tables = (const float*)d_in[1];
    float* out = (float*)d_out;
    const int n = in_sizes[0] / 3;

    // ws layout: hist(128K) | base(128K) | pts float4 (16n) | ws2 (8 levels * 8B * n)
    const size_t need = 262144 + (size_t)n * 16 + (size_t)n * 64;
    if (ws_size < need) {
        const int blocks = (n * NLVL + 255) / 256;
        hipLaunchKernelGGL(hashgrid_direct, dim3(blocks), dim3(256), 0, stream, x, tables, out, n);
        return;
    }

    char* w = (char*)d_ws;
    unsigned* hist = (unsigned*)w;
    unsigned* base = (unsigned*)(w + 131072);
    v4f* pts = (v4f*)(w + 262144);
    v2f* ws2 = (v2f*)(w + 262144 + (size_t)n * 16);

    const int pb = (n + 255) / 256;

    hipMemsetAsync(hist, 0, NBIN * sizeof(unsigned), stream);
    hipLaunchKernelGGL(gather_hash_u, dim3(pb * 8), dim3(256), 0, stream, x, tables, ws2, hist, n);
    hipLaunchKernelGGL(scan_kernel, dim3(1), dim3(1024), 0, stream, hist, base);
    hipLaunchKernelGGL(scatter_kernel, dim3(pb), dim3(256), 0, stream, x, base, pts, n);
    hipLaunchKernelGGL(dense_store, dim3(pb), dim3(256), 0, stream, pts, tables, out, n);
    hipLaunchKernelGGL(hash_store, dim3(pb), dim3(256), 0, stream, ws2, out, n);
}

// Round 9
// 398.251 us; speedup vs baseline: 1.1592x; 1.1592x over previous
//
#include <hip/hip_runtime.h>

#define NLVL 16
#define T_MASK ((1u << 19) - 1)
#define NBIN 32768   // 32^3 Morton bins

typedef float v2f __attribute__((ext_vector_type(2)));
typedef float v4f __attribute__((ext_vector_type(4)));

// Runtime-indexed copies (hash kernel, fallback)
__constant__ int c_res[NLVL] = {16, 20, 25, 32, 40, 50, 64, 80,
                                101, 128, 161, 203, 256, 322, 406, 512};
__constant__ int c_off[NLVL] = {0, 4913, 14174, 31750, 67687, 136608, 269259, 543884,
                                1075325, 1599613, 2123901, 2648189, 3172477, 3696765, 4221053, 4745341};
__constant__ float c_grid[NLVL] = {
    (float)(2.0 / 16.0),  (float)(2.0 / 20.0),  (float)(2.0 / 25.0),  (float)(2.0 / 32.0),
    (float)(2.0 / 40.0),  (float)(2.0 / 50.0),  (float)(2.0 / 64.0),  (float)(2.0 / 80.0),
    (float)(2.0 / 101.0), (float)(2.0 / 128.0), (float)(2.0 / 161.0), (float)(2.0 / 203.0),
    (float)(2.0 / 256.0), (float)(2.0 / 322.0), (float)(2.0 / 406.0), (float)(2.0 / 512.0)};

// Compile-time copies (dense kernel, fully unrolled -> immediates)
constexpr int kRes[8] = {16, 20, 25, 32, 40, 50, 64, 80};
constexpr int kOff[8] = {0, 4913, 14174, 31750, 67687, 136608, 269259, 543884};
constexpr float kGrid[8] = {
    (float)(2.0 / 16.0), (float)(2.0 / 20.0), (float)(2.0 / 25.0), (float)(2.0 / 32.0),
    (float)(2.0 / 40.0), (float)(2.0 / 50.0), (float)(2.0 / 64.0), (float)(2.0 / 80.0)};

__device__ __forceinline__ void dim_setup(float xv, float grid, int& b, float& w) {
    float xc = fminf(fmaxf(xv, -1.0f), 1.0f);
    float fb = floorf((xc + 1.0f) / grid);
    b = (int)fb;
    float vmin = fb * grid - 1.0f;
    w = (xv - vmin) / grid;   // original xv, exactly as reference
}

__device__ __forceinline__ unsigned part1by2(unsigned v) {
    v &= 0x3ff;
    v = (v | (v << 16)) & 0x030000FFu;
    v = (v | (v << 8))  & 0x0300F00Fu;
    v = (v | (v << 4))  & 0x030C30C3u;
    v = (v | (v << 2))  & 0x09249249u;
    return v;
}

__device__ __forceinline__ unsigned bin3(float a, float b, float c) {
    int ba = (int)floorf((a + 1.0f) * 16.0f); ba = ba < 0 ? 0 : (ba > 31 ? 31 : ba);
    int bb = (int)floorf((b + 1.0f) * 16.0f); bb = bb < 0 ? 0 : (bb > 31 ? 31 : bb);
    int bc = (int)floorf((c + 1.0f) * 16.0f); bc = bc < 0 ? 0 : (bc > 31 ? 31 : bc);
    return part1by2((unsigned)ba) | (part1by2((unsigned)bb) << 1) | (part1by2((unsigned)bc) << 2);
}

// ---- sort pipeline -------------------------------------------------------
__global__ __launch_bounds__(256) void hist_kernel(const float* __restrict__ x,
                                                   unsigned* __restrict__ hist, int n) {
    __shared__ float lx[768];
    const int p0 = (int)blockIdx.x * 256;
    const int tid = (int)threadIdx.x;
    for (int i = tid; i < 768; i += 256) {
        int gi = p0 * 3 + i;
        lx[i] = (gi < n * 3) ? x[gi] : 0.0f;
    }
    __syncthreads();
    const int p = p0 + tid;
    if (p >= n) return;
    atomicAdd(&hist[bin3(lx[3 * tid], lx[3 * tid + 1], lx[3 * tid + 2])], 1u);
}

// LDS-resident scan over 32K bins (one block, 1024 threads); verified in r8.
__global__ __launch_bounds__(1024) void scan_kernel(const unsigned* __restrict__ hist,
                                                    unsigned* __restrict__ base) {
    __shared__ unsigned lh[NBIN + NBIN / 32];   // addr = g + (g>>5)
    __shared__ unsigned part[1024];
    __shared__ unsigned cbase[1024];
    const int t = (int)threadIdx.x;

#pragma unroll
    for (int i = 0; i < NBIN / 1024; ++i) {
        int g = i * 1024 + t;
        lh[g + (g >> 5)] = hist[g];
    }
    __syncthreads();

    unsigned run = 0;
#pragma unroll
    for (int i = 0; i < 32; ++i) {
        unsigned v = lh[t * 33 + i];
        lh[t * 33 + i] = run;
        run += v;
    }
    part[t] = run;
    __syncthreads();

    for (int off = 1; off < 1024; off <<= 1) {
        unsigned v = (t >= off) ? part[t - off] : 0u;
        __syncthreads();
        part[t] += v;
        __syncthreads();
    }
    cbase[t] = part[t] - run;
    __syncthreads();

#pragma unroll
    for (int i = 0; i < NBIN / 1024; ++i) {
        int g = i * 1024 + t;
        base[g] = lh[g + (g >> 5)] + cbase[g >> 5];
    }
}

// SoA outputs: r3 measured the hashed gather at 230 us with SoA coordinate
// reads vs 256 us with AoS v4f (25% less stream traffic -> less table
// eviction in each XCD's L2).
__global__ __launch_bounds__(256) void scatter_kernel(const float* __restrict__ x,
                                                      unsigned* __restrict__ base,
                                                      float* __restrict__ sx,
                                                      float* __restrict__ sy,
                                                      float* __restrict__ sz,
                                                      int* __restrict__ org, int n) {
    __shared__ float lx[768];
    const int p0 = (int)blockIdx.x * 256;
    const int tid = (int)threadIdx.x;
    for (int i = tid; i < 768; i += 256) {
        int gi = p0 * 3 + i;
        lx[i] = (gi < n * 3) ? x[gi] : 0.0f;
    }
    __syncthreads();
    const int p = p0 + tid;
    if (p >= n) return;
    float a = lx[3 * tid], b = lx[3 * tid + 1], c = lx[3 * tid + 2];
    unsigned slot = atomicAdd(&base[bin3(a, b, c)], 1u);
    sx[slot] = a; sy[slot] = b; sz[slot] = c; org[slot] = p;
}

// ---- hashed levels: one block = one level x 256 SORTED points (sorted
// order clusters exact-slot reuse in L1/L2; r8 showed unsorted is worse).
// level = (blockIdx&7)+8 -> XCD k serves exactly one 4 MB table (L2-resident).
__global__ __launch_bounds__(256) void gather_hash(const float* __restrict__ sx,
                                                   const float* __restrict__ sy,
                                                   const float* __restrict__ sz,
                                                   const float* __restrict__ tables,
                                                   v2f* __restrict__ ws2, int n) {
    const int level = (int)(blockIdx.x & 7) + 8;
    const int p = (int)(blockIdx.x >> 3) * 256 + (int)threadIdx.x;
    if (p >= n) return;

    const float xx = sx[p], xy = sy[p], xz = sz[p];
    const float grid = c_grid[level];
    const v2f* __restrict__ tab = reinterpret_cast<const v2f*>(tables) + c_off[level];

    int bx, by, bz;
    float wx, wy, wz;
    dim_setup(xx, grid, bx, wx);
    dim_setup(xy, grid, by, wy);
    dim_setup(xz, grid, bz, wz);

    const unsigned hx0 = (unsigned)bx, hx1 = (unsigned)(bx + 1);
    const unsigned hy0 = (unsigned)by * 2654435761u;
    const unsigned hy1 = (unsigned)(by + 1) * 2654435761u;
    const unsigned hz0 = (unsigned)bz * 805459861u;
    const unsigned hz1 = (unsigned)(bz + 1) * 805459861u;
    v2f e0 = tab[(hx0 ^ hy0 ^ hz0) & T_MASK];
    v2f e1 = tab[(hx0 ^ hy0 ^ hz1) & T_MASK];
    v2f e2 = tab[(hx0 ^ hy1 ^ hz0) & T_MASK];
    v2f e3 = tab[(hx0 ^ hy1 ^ hz1) & T_MASK];
    v2f e4 = tab[(hx1 ^ hy0 ^ hz0) & T_MASK];
    v2f e5 = tab[(hx1 ^ hy0 ^ hz1) & T_MASK];
    v2f e6 = tab[(hx1 ^ hy1 ^ hz0) & T_MASK];
    v2f e7 = tab[(hx1 ^ hy1 ^ hz1) & T_MASK];

    const float ox = 1.0f - wx, oy = 1.0f - wy, oz = 1.0f - wz;
    v2f c00 = e0 * ox + e4 * wx;
    v2f c01 = e1 * ox + e5 * wx;
    v2f c10 = e2 * ox + e6 * wx;
    v2f c11 = e3 * ox + e7 * wx;
    v2f c0 = c00 * oy + c10 * wy;
    v2f c1 = c01 * oy + c11 * wy;
    v2f r = c0 * oz + c1 * wz;

    // lane-contiguous -> wave-coalesced full lines; NT keeps tables resident
    __builtin_nontemporal_store(r, &ws2[(size_t)(level - 8) * n + p]);
}

// ---- dense levels + final row assembly (r7 structure, SoA reads) ---------
// One thread = one sorted point; output rows staged in LDS then written with
// 8 lanes per row so every 64 B line is covered by ONE store instruction.
#define ROWSTRIDE 36   // floats per LDS row slot (144 B, keeps 16B alignment)
__global__ __launch_bounds__(256, 4) void dense_finish(const float* __restrict__ sx,
                                                       const float* __restrict__ sy,
                                                       const float* __restrict__ sz,
                                                       const int* __restrict__ org,
                                                       const float* __restrict__ tables,
                                                       const v2f* __restrict__ ws2,
                                                       float* __restrict__ out, int n) {
    __shared__ float lrow[256 * ROWSTRIDE];   // 36.9 KB
    __shared__ int lorg[256];

    const int nb = (int)gridDim.x;
    const int bid = (int)blockIdx.x;
    const int q = nb >> 3, r = nb & 7;
    const int xcd = bid & 7, j = bid >> 3;
    const int nbid = (xcd < r) ? xcd * (q + 1) + j : r * (q + 1) + (xcd - r) * q + j;
    const int tid = (int)threadIdx.x;
    const int base_p = nbid * 256;
    const int p = base_p + tid;

    if (p < n) {
        // issue the long-latency streaming loads first
        v2f h[8];
#pragma unroll
        for (int l = 0; l < 8; ++l)
            h[l] = __builtin_nontemporal_load(&ws2[(size_t)l * n + p]);

        const float xx = __builtin_nontemporal_load(&sx[p]);
        const float xy = __builtin_nontemporal_load(&sy[p]);
        const float xz = __builtin_nontemporal_load(&sz[p]);
        lorg[tid] = __builtin_nontemporal_load(&org[p]);

        v2f d[8];
#pragma unroll
        for (int l = 0; l < 8; ++l) {
            const int res = kRes[l];
            const float grid = kGrid[l];
            const v2f* __restrict__ tab = reinterpret_cast<const v2f*>(tables) + kOff[l];
            int bx, by, bz;
            float wx, wy, wz;
            dim_setup(xx, grid, bx, wx);
            dim_setup(xy, grid, by, wy);
            dim_setup(xz, grid, bz, wz);
            const int r2 = res * res;
            const int base = bx * r2 + by * res + bz;
            v2f e0 = tab[base];            v2f e1 = tab[base + 1];
            v2f e2 = tab[base + res];      v2f e3 = tab[base + res + 1];
            v2f e4 = tab[base + r2];       v2f e5 = tab[base + r2 + 1];
            v2f e6 = tab[base + r2 + res]; v2f e7 = tab[base + r2 + res + 1];
            const float ox = 1.0f - wx, oy = 1.0f - wy, oz = 1.0f - wz;
            v2f c00 = e0 * ox + e4 * wx;
            v2f c01 = e1 * ox + e5 * wx;
            v2f c10 = e2 * ox + e6 * wx;
            v2f c11 = e3 * ox + e7 * wx;
            v2f c0 = c00 * oy + c10 * wy;
            v2f c1 = c01 * oy + c11 * wy;
            d[l] = c0 * oz + c1 * wz;
        }

        float* myrow = &lrow[tid * ROWSTRIDE];
#pragma unroll
        for (int k = 0; k < 4; ++k) {
            v4f v; v.x = d[2 * k].x; v.y = d[2 * k].y; v.z = d[2 * k + 1].x; v.w = d[2 * k + 1].y;
            *reinterpret_cast<v4f*>(myrow + 4 * k) = v;
        }
#pragma unroll
        for (int k = 0; k < 4; ++k) {
            v4f v; v.x = h[2 * k].x; v.y = h[2 * k].y; v.z = h[2 * k + 1].x; v.w = h[2 * k + 1].y;
            *reinterpret_cast<v4f*>(myrow + 16 + 4 * k) = v;
        }
    }
    __syncthreads();

    // store phase: 8 consecutive lanes write one row's 128 B contiguously
    const int c = tid & 7;          // 16B chunk within row
    const int r0 = tid >> 3;        // 0..31
#pragma unroll
    for (int s = 0; s < 8; ++s) {
        const int rr = s * 32 + r0;                 // row within block
        if (base_p + rr < n) {
            v4f v = *reinterpret_cast<const v4f*>(&lrow[rr * ROWSTRIDE + c * 4]);
            const int o = lorg[rr];
            *reinterpret_cast<v4f*>(out + (size_t)o * 32 + c * 4) = v;
        }
    }
}

// ---- safety fallback (ws too small) --------------------------------------
__global__ __launch_bounds__(256) void hashgrid_direct(const float* __restrict__ x,
                                                       const float* __restrict__ tables,
                                                       float* __restrict__ out, int n_points) {
    const int t = (int)blockIdx.x * 256 + (int)threadIdx.x;
    const int p = t >> 4;
    if (p >= n_points) return;
    const int l = t & 15;
    const float xx = x[p * 3 + 0], xy = x[p * 3 + 1], xz = x[p * 3 + 2];
    const int res = c_res[l];
    const float grid = c_grid[l];
    const v2f* __restrict__ tab = reinterpret_cast<const v2f*>(tables) + c_off[l];
    int bx, by, bz; float wx, wy, wz;
    dim_setup(xx, grid, bx, wx);
    dim_setup(xy, grid, by, wy);
    dim_setup(xz, grid, bz, wz);
    v2f e0, e1, e2, e3, e4, e5, e6, e7;
    if (l < 8) {
        const int r2 = res * res;
        const int base = bx * r2 + by * res + bz;
        e0 = tab[base];            e1 = tab[base + 1];
        e2 = tab[base + res];      e3 = tab[base + res + 1];
        e4 = tab[base + r2];       e5 = tab[base + r2 + 1];
        e6 = tab[base + r2 + res]; e7 = tab[base + r2 + res + 1];
    } else {
        const unsigned hx0 = (unsigned)bx, hx1 = (unsigned)(bx + 1);
        const unsigned hy0 = (unsigned)by * 2654435761u, hy1 = (unsigned)(by + 1) * 2654435761u;
        const unsigned hz0 = (unsigned)bz * 805459861u,  hz1 = (unsigned)(bz + 1) * 805459861u;
        e0 = tab[(hx0 ^ hy0 ^ hz0) & T_MASK]; e1 = tab[(hx0 ^ hy0 ^ hz1) & T_MASK];
        e2 = tab[(hx0 ^ hy1 ^ hz0) & T_MASK]; e3 = tab[(hx0 ^ hy1 ^ hz1) & T_MASK];
        e4 = tab[(hx1 ^ hy0 ^ hz0) & T_MASK]; e5 = tab[(hx1 ^ hy0 ^ hz1) & T_MASK];
        e6 = tab[(hx1 ^ hy1 ^ hz0) & T_MASK]; e7 = tab[(hx1 ^ hy1 ^ hz1) & T_MASK];
    }
    const float ox = 1.0f - wx, oy = 1.0f - wy, oz = 1.0f - wz;
    v2f c00 = e0 * ox + e4 * wx, c01 = e1 * ox + e5 * wx;
    v2f c10 = e2 * ox + e6 * wx, c11 = e3 * ox + e7 * wx;
    v2f c0 = c00 * oy + c10 * wy, c1 = c01 * oy + c11 * wy;
    v2f r = c0 * oz + c1 * wz;
    reinterpret_cast<v2f*>(out)[(size_t)p * NLVL + l] = r;
}

extern "C" void kernel_launch(void* const* d_in, const int* in_sizes, int n_in,
                              void* d_out, int out_size, void* d_ws, size_t ws_size,
                              hipStream_t stream) {
    const float* x = (const float*)d_in[0];
    const float* tables = (const float*)d_in[1];
    float* out = (float*)d_out;
    const int n = in_sizes[0] / 3;

    // ws layout: hist(128K) | base(128K) | sx,sy,sz,org (4*4n) | ws2 (64n B)
    const size_t need = 262144 + (size_t)n * 16 + (size_t)n * 64;
    if (ws_size < need) {
        const int blocks = (n * NLVL + 255) / 256;
        hipLaunchKernelGGL(hashgrid_direct, dim3(blocks), dim3(256), 0, stream, x, tables, out, n);
        return;
    }

    char* w = (char*)d_ws;
    unsigned* hist = (unsigned*)w;
    unsigned* base = (unsigned*)(w + 131072);
    float* sx = (float*)(w + 262144);
    float* sy = sx + n;
    float* sz = sy + n;
    int* org = (int*)(sz + n);
    v2f* ws2 = (v2f*)(w + 262144 + (size_t)n * 16);

    const int pb = (n + 255) / 256;

    hipMemsetAsync(hist, 0, NBIN * sizeof(unsigned), stream);
    hipLaunchKernelGGL(hist_kernel, dim3(pb), dim3(256), 0, stream, x, hist, n);
    hipLaunchKernelGGL(scan_kernel, dim3(1), dim3(1024), 0, stream, hist, base);
    hipLaunchKernelGGL(scatter_kernel, dim3(pb), dim3(256), 0, stream, x, base, sx, sy, sz, org, n);
    hipLaunchKernelGGL(gather_hash, dim3(pb * 8), dim3(256), 0, stream, sx, sy, sz, tables, ws2, n);
    hipLaunchKernelGGL(dense_finish, dim3(pb), dim3(256), 0, stream, sx, sy, sz, org, tables, ws2, out, n);
}